// Round 13
// baseline (536.206 us; speedup 1.0000x reference)
//
#include <hip/hip_runtime.h>

// Steerable pyramid via MFMA (bf16 matrix cores), fp32 I/O.
// Depthwise conv as banded-matrix MFMA: D[px][ch] = sum_dy A_dy * B_dy,
// A_dy[m][k] = filt[dy][k-m-shift] (built in regs), B_dy[k][c] = input row
// in channel-major bf16 layout [n][y][c][x].  mfma_f32_16x16x32_bf16
// lane maps: A: m=l&15, k=(l>>4)*8+i; B: c=l&15, k=(l>>4)*8+i;
// D: c=l&15, m=(l>>4)*4+reg  [m89-verified].  r12 passed numerically
// (absmax 16384 << 46202) but spilled A (144 VGPR vs 128 cap).
// r13: bands = filter-outer (A[9] only, ~80 VGPR); dual/down get full
// register budget (no min-waves clamp); staging kernels vectorized.

typedef __attribute__((ext_vector_type(8))) short short8v;
typedef __attribute__((ext_vector_type(4))) float f32x4;

static __device__ __forceinline__ unsigned short f2bf(float f) {
    union { float f; unsigned u; } v; v.f = f;
    unsigned u = v.u;
    u += 0x7fffu + ((u >> 16) & 1u);
    return (unsigned short)(u >> 16);
}

static __device__ __forceinline__ unsigned pack2(float a, float b) {
    return (unsigned)f2bf(a) | ((unsigned)f2bf(b) << 16);
}

static __device__ __forceinline__ void nt_storef(float* p, float v) {
    __builtin_nontemporal_store(v, p);
}

// ---------------------------------------------------------------- staging

// fp32 NHWC image -> bf16 CX buffer [n][yp 264][c 16][x 264], pad 4, zeros.
// Thread = (n, yp, c, xg): 8 clamped scalar loads -> one short8v store.
__global__ __launch_bounds__(256) void img_to_cx(
    const float* __restrict__ src, unsigned short* __restrict__ dst)
{
    int id = blockIdx.x * 256 + threadIdx.x;     // < 8*264*16*33
    int n  = id / 139392;
    int r  = id - n * 139392;
    int yp = r / 528;
    int r2 = r - yp * 528;
    int c  = r2 / 33;
    int xg = r2 - c * 33;
    int y  = yp - 4;
    bool yok = (unsigned)y < 256u;
    int yc = min(max(y, 0), 255);

    short8v o;
    #pragma unroll
    for (int i = 0; i < 8; ++i) {
        int xs = xg * 8 + i - 4;
        bool ok = yok && ((unsigned)xs < 256u);
        int xc = min(max(xs, 0), 255);
        float v = src[(((size_t)(n * 256 + yc) * 256 + xc) << 4) + c];
        o[i] = (short)(ok ? f2bf(v) : 0);
    }
    *(short8v*)(dst + ((size_t)(n * 264 + yp) * 16 + c) * 264 + xg * 8) = o;
}

// Zero the 8-wide pad borders of the CX lo buffers, 16B stores.
// Vec-tasks per level: L0 135168, L1 69632, L2 36864, L3 20480 = 262144.
static __device__ __forceinline__ void zero_cx_vec(
    unsigned short* buf, int W, int id)
{
    int Wp = W + 16, Wv = Wp >> 3;
    int rowT = 16 * 16 * Wv;                     // pad rows, all c, vec x
    int perN = rowT + W * 32;                    // + col borders (2 per row*c)
    int n = id / perN;
    int r = id - n * perN;
    int y, c, xv;
    if (r < rowT) {
        int ry = r / (16 * Wv);
        int rem = r - ry * (16 * Wv);
        c = rem / Wv;
        xv = rem - c * Wv;
        y = (ry < 8) ? ry : ry + W;
    } else {
        int r2 = r - rowT;
        y = 8 + (r2 >> 5);
        int rem = r2 & 31;
        c = rem >> 1;
        xv = (rem & 1) ? (Wv - 1) : 0;
    }
    short8v z = {0, 0, 0, 0, 0, 0, 0, 0};
    *(short8v*)(buf + ((size_t)(n * Wp + y) * 16 + c) * Wp + xv * 8) = z;
}

__global__ __launch_bounds__(256) void zero_pads_cx(
    unsigned short* __restrict__ L0, unsigned short* __restrict__ L1,
    unsigned short* __restrict__ L2, unsigned short* __restrict__ L3,
    unsigned short* __restrict__ imgSlack)
{
    int b = blockIdx.x, t = threadIdx.x;
    if (b < 528)       zero_cx_vec(L0, 256, b * 256 + t);
    else if (b < 800)  zero_cx_vec(L1, 128, (b - 528) * 256 + t);
    else if (b < 944)  zero_cx_vec(L2, 64,  (b - 800) * 256 + t);
    else if (b < 1024) zero_cx_vec(L3, 32,  (b - 944) * 256 + t);
    else if (t < 32)   imgSlack[t] = 0;
}

// ---------------------------------------------------------------- MFMA convs

#define MFMA_BF16 __builtin_amdgcn_mfma_f32_16x16x32_bf16

// hi0 + lo0 from IMG CX (pad 4). 512 blocks: n=b&7, q=b>>3: xseg=q&15, yq=q>>4.
__global__ __launch_bounds__(256) void dual_mfma(
    const unsigned short* __restrict__ img,
    float* __restrict__ hi0, unsigned short* __restrict__ lo0,
    const float* __restrict__ fh, const float* __restrict__ fl)
{
    const int RS = 16 * 264;
    int n = blockIdx.x & 7;
    int q = blockIdx.x >> 3;
    int xseg = q & 15, yq = q >> 4;
    int t = threadIdx.x, wv = t >> 6, l = t & 63;
    int m = l & 15, g = l >> 4, kb = g * 8;
    int x0 = xseg * 16;
    int ybase = (yq * 4 + wv) * 16;

    short8v Ah[9], Al[9];
    #pragma unroll
    for (int dy = 0; dy < 9; ++dy) {
        const float* fhr = fh + dy * 9;
        const float* flr = fl + dy * 9;
        short8v ah, al;
        #pragma unroll
        for (int i = 0; i < 8; ++i) {
            int d = kb + i - m;
            bool ok = (d >= 0) && (d < 9);
            ah[i] = (short)(ok ? f2bf(fhr[d]) : 0);
            al[i] = (short)(ok ? f2bf(flr[d]) : 0);
        }
        Ah[dy] = ah; Al[dy] = al;
    }

    #pragma unroll 1
    for (int ty = 0; ty < 16; ++ty) {
        int y = ybase + ty;
        const unsigned short* base =
            img + ((size_t)(n * 264 + y) * 16 + m) * 264 + x0 + kb;
        f32x4 ach = {0, 0, 0, 0}, acl = {0, 0, 0, 0};
        #pragma unroll
        for (int dy = 0; dy < 9; ++dy) {
            short8v B = *(const short8v*)(base + (size_t)dy * RS);
            ach = MFMA_BF16(Ah[dy], B, ach, 0, 0, 0);
            acl = MFMA_BF16(Al[dy], B, acl, 0, 0, 0);
        }
        size_t ob = ((size_t)(n * 256 + y) * 256 + x0 + g * 4) * 16 + m;
        #pragma unroll
        for (int r = 0; r < 4; ++r) nt_storef(hi0 + ob + (size_t)r * 16, ach[r]);
        size_t lb = ((size_t)(n * 272 + y + 8) * 16 + m) * 272 + (x0 + 8 + g * 4);
        *(unsigned*)(lo0 + lb)     = pack2(acl[0], acl[1]);
        *(unsigned*)(lo0 + lb + 2) = pack2(acl[2], acl[3]);
    }
}

// 4 band convs from CX lo (pad 8), FILTER-OUTER: A[9] (36 VGPR) per band,
// y-tiles swept inside. col = x0 + k, k = m + dx + 4.
template <int LOGW, int YPW>
__global__ __launch_bounds__(256) void bands_mfma(
    const unsigned short* __restrict__ in,
    float* __restrict__ b0, float* __restrict__ b1,
    float* __restrict__ b2, float* __restrict__ b3,
    const float* __restrict__ bf)
{
    const int W = 1 << LOGW, Wp = W + 16, XS = W / 16, RS = 16 * Wp;
    int n = blockIdx.x & 7;
    int q = blockIdx.x >> 3;
    int xseg = q & (XS - 1), yq = q >> (LOGW - 4);
    int t = threadIdx.x, wv = t >> 6, l = t & 63;
    int m = l & 15, g = l >> 4, kb = g * 8;
    int x0 = xseg * 16;
    int ybase = (yq * 4 + wv) * YPW;

    #pragma unroll 1
    for (int f = 0; f < 4; ++f) {
        const float* fr = bf + f * 81;
        short8v A[9];
        #pragma unroll
        for (int dy = 0; dy < 9; ++dy) {
            short8v a;
            #pragma unroll
            for (int i = 0; i < 8; ++i) {
                int d = kb + i - m - 4;
                a[i] = (short)((d >= 0 && d < 9) ? f2bf(fr[dy * 9 + d]) : 0);
            }
            A[dy] = a;
        }
        float* ob = (f == 0) ? b0 : (f == 1) ? b1 : (f == 2) ? b2 : b3;

        #pragma unroll 1
        for (int ty = 0; ty < YPW; ++ty) {
            int y = ybase + ty;
            const unsigned short* base =
                in + ((size_t)(n * Wp + y + 4) * 16 + m) * Wp + x0 + kb;
            f32x4 acc = {0, 0, 0, 0};
            #pragma unroll
            for (int dy = 0; dy < 9; ++dy) {
                short8v B = *(const short8v*)(base + (size_t)dy * RS);
                acc = MFMA_BF16(A[dy], B, acc, 0, 0, 0);
            }
            size_t oi = ((size_t)(n * W + y) * W + x0 + g * 4) * 16 + m;
            #pragma unroll
            for (int r = 0; r < 4; ++r) nt_storef(ob + oi + (size_t)r * 16, acc[r]);
        }
    }
}

// 17x17 stride-2 downsample from CX lo (pad 8). col = 2*x0 + k, k = 2m + dx.
// Two MFMAs per dy (k-split); lanes g>=2 have A2==0, B2 addr clamped in-bounds.
template <int LOGW, int YPW, bool OUTF32>
__global__ __launch_bounds__(256) void down_mfma(
    const unsigned short* __restrict__ in, void* __restrict__ outp,
    const float* __restrict__ lf)
{
    const int W = 1 << LOGW, Wpi = W + 16, Wo = W >> 1, Wpo = Wo + 16;
    const int XS = Wo / 16, RS = 16 * Wpi;
    int n = blockIdx.x & 7;
    int q = blockIdx.x >> 3;
    int xseg = q & (XS - 1), yq = q >> (LOGW - 5);
    int t = threadIdx.x, wv = t >> 6, l = t & 63;
    int m = l & 15, g = l >> 4, kb = g * 8;
    int x0 = xseg * 16;
    int ybase = (yq * 4 + wv) * YPW;
    int off2 = (g < 2) ? 32 : 0;

    short8v A1[17], A2[17];
    #pragma unroll
    for (int dy = 0; dy < 17; ++dy) {
        const float* fr = lf + dy * 17;
        short8v a1, a2;
        #pragma unroll
        for (int i = 0; i < 8; ++i) {
            int d1 = kb + i - 2 * m;
            int d2 = 32 + kb + i - 2 * m;
            a1[i] = (short)((d1 >= 0 && d1 < 17) ? f2bf(fr[d1]) : 0);
            a2[i] = (short)((d2 >= 0 && d2 < 17) ? f2bf(fr[d2]) : 0);
        }
        A1[dy] = a1; A2[dy] = a2;
    }

    #pragma unroll 1
    for (int ty = 0; ty < YPW; ++ty) {
        int yo = ybase + ty;
        const unsigned short* base =
            in + ((size_t)(n * Wpi + 2 * yo) * 16 + m) * Wpi + 2 * x0 + kb;
        f32x4 aA = {0, 0, 0, 0}, aB = {0, 0, 0, 0};
        #pragma unroll
        for (int dy = 0; dy < 17; ++dy) {
            short8v B1 = *(const short8v*)(base + (size_t)dy * RS);
            short8v B2 = *(const short8v*)(base + (size_t)dy * RS + off2);
            aA = MFMA_BF16(A1[dy], B1, aA, 0, 0, 0);
            aB = MFMA_BF16(A2[dy], B2, aB, 0, 0, 0);
        }
        f32x4 acc = aA + aB;
        if (OUTF32) {
            float* o = (float*)outp;
            size_t ob = ((size_t)(n * Wo + yo) * Wo + x0 + g * 4) * 16 + m;
            #pragma unroll
            for (int r = 0; r < 4; ++r) nt_storef(o + ob + (size_t)r * 16, acc[r]);
        } else {
            unsigned short* o = (unsigned short*)outp;
            size_t lb = ((size_t)(n * Wpo + yo + 8) * 16 + m) * Wpo + (x0 + 8 + g * 4);
            *(unsigned*)(o + lb)     = pack2(acc[0], acc[1]);
            *(unsigned*)(o + lb + 2) = pack2(acc[2], acc[3]);
        }
    }
}

// ---------------------------------------------------------------- launch

extern "C" void kernel_launch(void* const* d_in, const int* in_sizes, int n_in,
                              void* d_out, int out_size, void* d_ws, size_t ws_size,
                              hipStream_t stream) {
    const float* image   = (const float*)d_in[0];
    const float* lo0filt = (const float*)d_in[1];
    const float* hi0filt = (const float*)d_in[2];
    const float* lofilt  = (const float*)d_in[3];
    const float* bfilts  = (const float*)d_in[4];
    float* out = (float*)d_out;

    const int N = 8, C = 16;
    size_t sz[5];
    const int Ws[5] = {256, 128, 64, 32, 16};
    for (int s = 0; s < 5; ++s) sz[s] = (size_t)N * Ws[s] * Ws[s] * C;

    // Workspace (ushort units): IMG CX (264^2 pad4) + slack, L0..L3 CX pad8.
    unsigned short* wsu = (unsigned short*)d_ws;
    unsigned short* IMG = wsu;
    size_t imgE = (size_t)N * 264 * 16 * 264;
    unsigned short* IMGSLACK = IMG + imgE;
    unsigned short* L0 = IMGSLACK + 32;
    unsigned short* L1 = L0 + (size_t)N * 272 * 16 * 272;
    unsigned short* L2 = L1 + (size_t)N * 144 * 16 * 144;
    unsigned short* L3 = L2 + (size_t)N * 80 * 16 * 80;

    // Output layout (reversed pyramid, flat):
    // [ lo_final | s=3 b=3..0 | s=2 b=3..0 | s=1 b=3..0 | s=0 b=3..0 | hi0 ]
    float* out_lofinal = out;
    size_t o = sz[4];
    float* band_ptr[4][4];
    for (int s = 3; s >= 0; --s)
        for (int b = 3; b >= 0; --b) { band_ptr[s][b] = out + o; o += sz[s]; }
    float* out_hi0 = out + o;

    zero_pads_cx<<<1025, 256, 0, stream>>>(L0, L1, L2, L3, IMGSLACK);
    img_to_cx<<<4356, 256, 0, stream>>>(image, IMG);
    dual_mfma<<<512, 256, 0, stream>>>(IMG, out_hi0, L0, hi0filt, lo0filt);
    down_mfma<8, 16, false><<<128, 256, 0, stream>>>(L0, L1, lofilt);
    bands_mfma<8, 16><<<512, 256, 0, stream>>>(
        L0, band_ptr[0][0], band_ptr[0][1], band_ptr[0][2], band_ptr[0][3], bfilts);
    down_mfma<7, 16, false><<<32, 256, 0, stream>>>(L1, L2, lofilt);
    bands_mfma<7, 16><<<128, 256, 0, stream>>>(
        L1, band_ptr[1][0], band_ptr[1][1], band_ptr[1][2], band_ptr[1][3], bfilts);
    down_mfma<6, 8, false><<<16, 256, 0, stream>>>(L2, L3, lofilt);
    bands_mfma<6, 16><<<32, 256, 0, stream>>>(
        L2, band_ptr[2][0], band_ptr[2][1], band_ptr[2][2], band_ptr[2][3], bfilts);
    down_mfma<5, 4, true><<<8, 256, 0, stream>>>(L3, out_lofinal, lofilt);
    bands_mfma<5, 8><<<16, 256, 0, stream>>>(
        L3, band_ptr[3][0], band_ptr[3][1], band_ptr[3][2], band_ptr[3][3], bfilts);
}

// Round 14
// 265.249 us; speedup vs baseline: 2.0215x; 2.0215x over previous
//
#include <hip/hip_runtime.h>

// Steerable pyramid via MFMA (bf16 matrix cores), fp32 I/O.
// Depthwise conv as banded-matrix MFMA: D[px][ch] = sum_dy A_dy * B_dy,
// A_dy[m][k] = filt[dy][k-m-shift], B_dy[k][c] = input row in channel-major
// bf16 layout [n][y][c][x].  mfma_f32_16x16x32_bf16 lane maps:
// A: m=l&15, k=(l>>4)*8+i; B: c=l&15, k=(l>>4)*8+i; D: c=l&15, m=(l>>4)*4+reg.
// Numerics verified r12/r13 (absmax 16384 << 46202 threshold).
// r14: (1) YPW 16->4 => 4x grid (8 blocks/CU, TLP hides L2+MFMA latency);
// (2) A-fragments precomputed once to a ws table (build_frags) -> conv waves
// load them as coalesced 16B loads instead of ~400 VALU ops per filter.

typedef __attribute__((ext_vector_type(8))) short short8v;
typedef __attribute__((ext_vector_type(4))) float f32x4;

static __device__ __forceinline__ unsigned short f2bf(float f) {
    union { float f; unsigned u; } v; v.f = f;
    unsigned u = v.u;
    u += 0x7fffu + ((u >> 16) & 1u);
    return (unsigned short)(u >> 16);
}

static __device__ __forceinline__ unsigned pack2(float a, float b) {
    return (unsigned)f2bf(a) | ((unsigned)f2bf(b) << 16);
}

static __device__ __forceinline__ void nt_storef(float* p, float v) {
    __builtin_nontemporal_store(v, p);
}

// Fragment-table rows: [0..35] bands (f*9+dy); [36..44] dual-hi (dy);
// [45..53] dual-lo (dy); [54..70] down-A1 (dy); [71..87] down-A2 (dy).
// Entry: AF[(row*64 + lane)*8 .. +7] (short8v per lane).

// ---------------------------------------------------------------- staging

__global__ __launch_bounds__(256) void build_frags(
    const float* __restrict__ bf, const float* __restrict__ fh,
    const float* __restrict__ fl, const float* __restrict__ lfilt,
    unsigned short* __restrict__ AF)
{
    int id = blockIdx.x * 256 + threadIdx.x;     // < 5632
    if (id >= 88 * 64) return;
    int row = id >> 6, l = id & 63;
    int m = l & 15, kb = (l >> 4) * 8;
    short8v a;
    if (row < 36) {
        int f = row / 9, dy = row - f * 9;
        const float* fr = bf + f * 81 + dy * 9;
        #pragma unroll
        for (int i = 0; i < 8; ++i) {
            int d = kb + i - m - 4;
            a[i] = (short)((d >= 0 && d < 9) ? f2bf(fr[d]) : 0);
        }
    } else if (row < 54) {
        int r2 = row - 36;
        int f = r2 / 9, dy = r2 - f * 9;
        const float* fr = (f == 0 ? fh : fl) + dy * 9;
        #pragma unroll
        for (int i = 0; i < 8; ++i) {
            int d = kb + i - m;
            a[i] = (short)((d >= 0 && d < 9) ? f2bf(fr[d]) : 0);
        }
    } else {
        int r2 = row - 54;
        int p = r2 / 17, dy = r2 - p * 17;
        const float* fr = lfilt + dy * 17;
        #pragma unroll
        for (int i = 0; i < 8; ++i) {
            int d = kb + i - 2 * m + (p ? 32 : 0) - 0;
            d = kb + i - 2 * m + (p ? 32 : 0);
            a[i] = (short)((d >= 0 && d < 17) ? f2bf(fr[d]) : 0);
        }
    }
    *(short8v*)(AF + (size_t)id * 8) = a;
}

// fp32 NHWC image -> bf16 CX buffer [n][yp 264][c 16][x 264], pad 4, zeros.
__global__ __launch_bounds__(256) void img_to_cx(
    const float* __restrict__ src, unsigned short* __restrict__ dst)
{
    int id = blockIdx.x * 256 + threadIdx.x;     // < 8*264*16*33
    int n  = id / 139392;
    int r  = id - n * 139392;
    int yp = r / 528;
    int r2 = r - yp * 528;
    int c  = r2 / 33;
    int xg = r2 - c * 33;
    int y  = yp - 4;
    bool yok = (unsigned)y < 256u;
    int yc = min(max(y, 0), 255);

    short8v o;
    #pragma unroll
    for (int i = 0; i < 8; ++i) {
        int xs = xg * 8 + i - 4;
        bool ok = yok && ((unsigned)xs < 256u);
        int xc = min(max(xs, 0), 255);
        float v = src[(((size_t)(n * 256 + yc) * 256 + xc) << 4) + c];
        o[i] = (short)(ok ? f2bf(v) : 0);
    }
    *(short8v*)(dst + ((size_t)(n * 264 + yp) * 16 + c) * 264 + xg * 8) = o;
}

// Zero the 8-wide pad borders of the CX lo buffers, 16B stores.
static __device__ __forceinline__ void zero_cx_vec(
    unsigned short* buf, int W, int id)
{
    int Wp = W + 16, Wv = Wp >> 3;
    int rowT = 16 * 16 * Wv;
    int perN = rowT + W * 32;
    int n = id / perN;
    int r = id - n * perN;
    int y, c, xv;
    if (r < rowT) {
        int ry = r / (16 * Wv);
        int rem = r - ry * (16 * Wv);
        c = rem / Wv;
        xv = rem - c * Wv;
        y = (ry < 8) ? ry : ry + W;
    } else {
        int r2 = r - rowT;
        y = 8 + (r2 >> 5);
        int rem = r2 & 31;
        c = rem >> 1;
        xv = (rem & 1) ? (Wv - 1) : 0;
    }
    short8v z = {0, 0, 0, 0, 0, 0, 0, 0};
    *(short8v*)(buf + ((size_t)(n * Wp + y) * 16 + c) * Wp + xv * 8) = z;
}

__global__ __launch_bounds__(256) void zero_pads_cx(
    unsigned short* __restrict__ L0, unsigned short* __restrict__ L1,
    unsigned short* __restrict__ L2, unsigned short* __restrict__ L3)
{
    int b = blockIdx.x, t = threadIdx.x;
    if (b < 528)       zero_cx_vec(L0, 256, b * 256 + t);
    else if (b < 800)  zero_cx_vec(L1, 128, (b - 528) * 256 + t);
    else if (b < 944)  zero_cx_vec(L2, 64,  (b - 800) * 256 + t);
    else if (b < 1024) zero_cx_vec(L3, 32,  (b - 944) * 256 + t);
}

// ---------------------------------------------------------------- MFMA convs

#define MFMA_BF16 __builtin_amdgcn_mfma_f32_16x16x32_bf16

// hi0 + lo0 from IMG CX (pad 4). YPW=4. grid 2048: n=b&7, q=b>>3:
// xseg=q&15, yq=q>>4; ybase=(yq*4+wv)*4.
__global__ __launch_bounds__(256) void dual_mfma(
    const unsigned short* __restrict__ img,
    float* __restrict__ hi0, unsigned short* __restrict__ lo0,
    const unsigned short* __restrict__ AF)
{
    const int RS = 16 * 264;
    int n = blockIdx.x & 7;
    int q = blockIdx.x >> 3;
    int xseg = q & 15, yq = q >> 4;
    int t = threadIdx.x, wv = t >> 6, l = t & 63;
    int m = l & 15, g = l >> 4, kb = g * 8;
    int x0 = xseg * 16;
    int ybase = (yq * 4 + wv) * 4;

    short8v Ah[9], Al[9];
    #pragma unroll
    for (int dy = 0; dy < 9; ++dy) {
        Ah[dy] = *(const short8v*)(AF + ((size_t)((36 + dy) * 64 + l)) * 8);
        Al[dy] = *(const short8v*)(AF + ((size_t)((45 + dy) * 64 + l)) * 8);
    }

    #pragma unroll 1
    for (int ty = 0; ty < 4; ++ty) {
        int y = ybase + ty;
        const unsigned short* base =
            img + ((size_t)(n * 264 + y) * 16 + m) * 264 + x0 + kb;
        f32x4 ach = {0, 0, 0, 0}, acl = {0, 0, 0, 0};
        #pragma unroll
        for (int dy = 0; dy < 9; ++dy) {
            short8v B = *(const short8v*)(base + (size_t)dy * RS);
            ach = MFMA_BF16(Ah[dy], B, ach, 0, 0, 0);
            acl = MFMA_BF16(Al[dy], B, acl, 0, 0, 0);
        }
        size_t ob = ((size_t)(n * 256 + y) * 256 + x0 + g * 4) * 16 + m;
        #pragma unroll
        for (int r = 0; r < 4; ++r) nt_storef(hi0 + ob + (size_t)r * 16, ach[r]);
        size_t lb = ((size_t)(n * 272 + y + 8) * 16 + m) * 272 + (x0 + 8 + g * 4);
        *(unsigned*)(lo0 + lb)     = pack2(acl[0], acl[1]);
        *(unsigned*)(lo0 + lb + 2) = pack2(acl[2], acl[3]);
    }
}

// 4 band convs from CX lo (pad 8), filter-outer, A from table. YPW=4.
// grid/8 = (W/16)^2: xseg=q&(XS-1), yq=q>>(LOGW-4).
template <int LOGW>
__global__ __launch_bounds__(256) void bands_mfma(
    const unsigned short* __restrict__ in,
    float* __restrict__ b0, float* __restrict__ b1,
    float* __restrict__ b2, float* __restrict__ b3,
    const unsigned short* __restrict__ AF)
{
    const int W = 1 << LOGW, Wp = W + 16, XS = W / 16, RS = 16 * Wp;
    int n = blockIdx.x & 7;
    int q = blockIdx.x >> 3;
    int xseg = q & (XS - 1), yq = q >> (LOGW - 4);
    int t = threadIdx.x, wv = t >> 6, l = t & 63;
    int m = l & 15, g = l >> 4, kb = g * 8;
    int x0 = xseg * 16;
    int ybase = (yq * 4 + wv) * 4;

    #pragma unroll 1
    for (int f = 0; f < 4; ++f) {
        short8v A[9];
        #pragma unroll
        for (int dy = 0; dy < 9; ++dy)
            A[dy] = *(const short8v*)(AF + ((size_t)((f * 9 + dy) * 64 + l)) * 8);
        float* ob = (f == 0) ? b0 : (f == 1) ? b1 : (f == 2) ? b2 : b3;

        #pragma unroll 1
        for (int ty = 0; ty < 4; ++ty) {
            int y = ybase + ty;
            const unsigned short* base =
                in + ((size_t)(n * Wp + y + 4) * 16 + m) * Wp + x0 + kb;
            f32x4 acc = {0, 0, 0, 0};
            #pragma unroll
            for (int dy = 0; dy < 9; ++dy) {
                short8v B = *(const short8v*)(base + (size_t)dy * RS);
                acc = MFMA_BF16(A[dy], B, acc, 0, 0, 0);
            }
            size_t oi = ((size_t)(n * W + y) * W + x0 + g * 4) * 16 + m;
            #pragma unroll
            for (int r = 0; r < 4; ++r) nt_storef(ob + oi + (size_t)r * 16, acc[r]);
        }
    }
}

// 17x17 stride-2 downsample from CX lo (pad 8), A from table. YPW=4.
// grid/8 = (Wo/16)^2: xseg=q&(XS-1), yq=q>>(LOGW-5).
template <int LOGW, bool OUTF32>
__global__ __launch_bounds__(256) void down_mfma(
    const unsigned short* __restrict__ in, void* __restrict__ outp,
    const unsigned short* __restrict__ AF)
{
    const int W = 1 << LOGW, Wpi = W + 16, Wo = W >> 1, Wpo = Wo + 16;
    const int XS = Wo / 16, RS = 16 * Wpi;
    int n = blockIdx.x & 7;
    int q = blockIdx.x >> 3;
    int xseg = q & (XS - 1), yq = q >> (LOGW - 5);
    int t = threadIdx.x, wv = t >> 6, l = t & 63;
    int m = l & 15, g = l >> 4, kb = g * 8;
    int x0 = xseg * 16;
    int ybase = (yq * 4 + wv) * 4;
    int off2 = (g < 2) ? 32 : 0;

    short8v A1[17], A2[17];
    #pragma unroll
    for (int dy = 0; dy < 17; ++dy) {
        A1[dy] = *(const short8v*)(AF + ((size_t)((54 + dy) * 64 + l)) * 8);
        A2[dy] = *(const short8v*)(AF + ((size_t)((71 + dy) * 64 + l)) * 8);
    }

    #pragma unroll 1
    for (int ty = 0; ty < 4; ++ty) {
        int yo = ybase + ty;
        const unsigned short* base =
            in + ((size_t)(n * Wpi + 2 * yo) * 16 + m) * Wpi + 2 * x0 + kb;
        f32x4 aA = {0, 0, 0, 0}, aB = {0, 0, 0, 0};
        #pragma unroll
        for (int dy = 0; dy < 17; ++dy) {
            short8v B1 = *(const short8v*)(base + (size_t)dy * RS);
            short8v B2 = *(const short8v*)(base + (size_t)dy * RS + off2);
            aA = MFMA_BF16(A1[dy], B1, aA, 0, 0, 0);
            aB = MFMA_BF16(A2[dy], B2, aB, 0, 0, 0);
        }
        f32x4 acc = aA + aB;
        if (OUTF32) {
            float* o = (float*)outp;
            size_t ob = ((size_t)(n * Wo + yo) * Wo + x0 + g * 4) * 16 + m;
            #pragma unroll
            for (int r = 0; r < 4; ++r) nt_storef(o + ob + (size_t)r * 16, acc[r]);
        } else {
            unsigned short* o = (unsigned short*)outp;
            size_t lb = ((size_t)(n * Wpo + yo + 8) * 16 + m) * Wpo + (x0 + 8 + g * 4);
            *(unsigned*)(o + lb)     = pack2(acc[0], acc[1]);
            *(unsigned*)(o + lb + 2) = pack2(acc[2], acc[3]);
        }
    }
}

// ---------------------------------------------------------------- launch

extern "C" void kernel_launch(void* const* d_in, const int* in_sizes, int n_in,
                              void* d_out, int out_size, void* d_ws, size_t ws_size,
                              hipStream_t stream) {
    const float* image   = (const float*)d_in[0];
    const float* lo0filt = (const float*)d_in[1];
    const float* hi0filt = (const float*)d_in[2];
    const float* lofilt  = (const float*)d_in[3];
    const float* bfilts  = (const float*)d_in[4];
    float* out = (float*)d_out;

    const int N = 8, C = 16;
    size_t sz[5];
    const int Ws[5] = {256, 128, 64, 32, 16};
    for (int s = 0; s < 5; ++s) sz[s] = (size_t)N * Ws[s] * Ws[s] * C;

    // Workspace (ushort units): AF table, IMG CX (pad4), L0..L3 CX (pad8).
    unsigned short* wsu = (unsigned short*)d_ws;
    unsigned short* AF  = wsu;                       // 88*64*8 = 45056
    unsigned short* IMG = AF + 88 * 64 * 8;
    unsigned short* L0 = IMG + (size_t)N * 264 * 16 * 264;
    unsigned short* L1 = L0 + (size_t)N * 272 * 16 * 272;
    unsigned short* L2 = L1 + (size_t)N * 144 * 16 * 144;
    unsigned short* L3 = L2 + (size_t)N * 80 * 16 * 80;

    // Output layout (reversed pyramid, flat):
    // [ lo_final | s=3 b=3..0 | s=2 b=3..0 | s=1 b=3..0 | s=0 b=3..0 | hi0 ]
    float* out_lofinal = out;
    size_t o = sz[4];
    float* band_ptr[4][4];
    for (int s = 3; s >= 0; --s)
        for (int b = 3; b >= 0; --b) { band_ptr[s][b] = out + o; o += sz[s]; }
    float* out_hi0 = out + o;

    build_frags<<<22, 256, 0, stream>>>(bfilts, hi0filt, lo0filt, lofilt, AF);
    zero_pads_cx<<<1024, 256, 0, stream>>>(L0, L1, L2, L3);
    img_to_cx<<<4356, 256, 0, stream>>>(image, IMG);
    dual_mfma<<<2048, 256, 0, stream>>>(IMG, out_hi0, L0, AF);
    down_mfma<8, false><<<512, 256, 0, stream>>>(L0, L1, AF);
    bands_mfma<8><<<2048, 256, 0, stream>>>(
        L0, band_ptr[0][0], band_ptr[0][1], band_ptr[0][2], band_ptr[0][3], AF);
    down_mfma<7, false><<<128, 256, 0, stream>>>(L1, L2, AF);
    bands_mfma<7><<<512, 256, 0, stream>>>(
        L1, band_ptr[1][0], band_ptr[1][1], band_ptr[1][2], band_ptr[1][3], AF);
    down_mfma<6, false><<<32, 256, 0, stream>>>(L2, L3, AF);
    bands_mfma<6><<<128, 256, 0, stream>>>(
        L2, band_ptr[2][0], band_ptr[2][1], band_ptr[2][2], band_ptr[2][3], AF);
    down_mfma<5, true><<<8, 256, 0, stream>>>(L3, out_lofinal, AF);
    bands_mfma<5><<<32, 256, 0, stream>>>(
        L3, band_ptr[3][0], band_ptr[3][1], band_ptr[3][2], band_ptr[3][3], AF);
}

// Round 15
// 155.201 us; speedup vs baseline: 3.4549x; 1.7091x over previous
//
#include <hip/hip_runtime.h>

// Steerable pyramid via MFMA, fp32 I/O, bf16 compute (threshold = 2% of
// per-output absmax; bf16 error ~16384 << 46202, verified r12-r14).
// CX layout for staged images: [n][y][c 16][x] bf16, zero-padded.
//
// r15: 9-tap convs use mfma_f32_32x32x16_bf16 with fused M:
//  bands: M=32 = 4 bands x 8 px; k-window = px(8)+taps(9)-1 = 16 = K.
//    A[(f,p)][k] = filt_f[dy][k-p] (k-p in [0,9)), B[k][(pg,c)] =
//    row[x0+pg*8+k-4][c] -> ONE MFMA per dy covers 4 bands x 16 px x 16 ch.
//    9 loads + 9 MFMA per tile (was 36+36 filter-outer).
//  dual: M=32 = 2 rows x 2 filters x 8 px, 10 input rows i=0..9,
//    A_i[(ry,f,p)][k] = filt_f[i-ry][k-p] -> 10 loads + 10 MFMA per
//    2-row x 16 px tile (was 18+9 at 28% util).
//  D lane map (m74/m101): col=l&31, row=(reg&3)+8*(reg>>2)+4*(l>>5).
// down17 keeps 16x16x32 k-split (17 taps don't fit K=16).
// img_to_cx: coalesced float4 loads + LDS transpose (was scalar).

typedef __attribute__((ext_vector_type(8))) short short8v;
typedef __attribute__((ext_vector_type(4))) float f32x4;
typedef __attribute__((ext_vector_type(16))) float f32x16;

static __device__ __forceinline__ unsigned short f2bf(float f) {
    union { float f; unsigned u; } v; v.f = f;
    unsigned u = v.u;
    u += 0x7fffu + ((u >> 16) & 1u);
    return (unsigned short)(u >> 16);
}

static __device__ __forceinline__ unsigned pack2(float a, float b) {
    return (unsigned)f2bf(a) | ((unsigned)f2bf(b) << 16);
}

static __device__ __forceinline__ void nt_storef(float* p, float v) {
    __builtin_nontemporal_store(v, p);
}

// AF fragment table rows (entry = short8v per lane, row*64+l):
// [0..8]   bands32 dy        (M=(f,p))
// [9..18]  dual32 i=0..9     (M=(ry,f,p); f0=hi, f1=lo)
// [19..35] down A1 dy=0..16  (16x16x32 map)
// [36..52] down A2 dy=0..16

__global__ __launch_bounds__(256) void build_frags(
    const float* __restrict__ bf, const float* __restrict__ fh,
    const float* __restrict__ fl, const float* __restrict__ lfilt,
    unsigned short* __restrict__ AF)
{
    int id = blockIdx.x * 256 + threadIdx.x;
    if (id >= 53 * 64) return;
    int row = id >> 6, l = id & 63;
    short8v a;
    if (row < 9) {
        int dy = row;
        int m = l & 31, f = m >> 3, p = m & 7, kb = (l >> 5) * 8;
        #pragma unroll
        for (int i = 0; i < 8; ++i) {
            int d = kb + i - p;
            a[i] = (short)((d >= 0 && d < 9) ? f2bf(bf[f * 81 + dy * 9 + d]) : 0);
        }
    } else if (row < 19) {
        int is = row - 9;
        int m = l & 31, ry = m >> 4, f = (m >> 3) & 1, p = m & 7, kb = (l >> 5) * 8;
        int dy = is - ry;
        const float* fr = f ? fl : fh;
        #pragma unroll
        for (int i = 0; i < 8; ++i) {
            int dx = kb + i - p;
            bool ok = (dy >= 0 && dy < 9) && (dx >= 0 && dx < 9);
            a[i] = (short)(ok ? f2bf(fr[dy * 9 + dx]) : 0);
        }
    } else if (row < 36) {
        int dy = row - 19;
        int m = l & 15, kb = (l >> 4) * 8;
        #pragma unroll
        for (int i = 0; i < 8; ++i) {
            int d = kb + i - 2 * m;
            a[i] = (short)((d >= 0 && d < 17) ? f2bf(lfilt[dy * 17 + d]) : 0);
        }
    } else {
        int dy = row - 36;
        int m = l & 15, kb = (l >> 4) * 8;
        #pragma unroll
        for (int i = 0; i < 8; ++i) {
            int d = 32 + kb + i - 2 * m;
            a[i] = (short)((d >= 0 && d < 17) ? f2bf(lfilt[dy * 17 + d]) : 0);
        }
    }
    *(short8v*)(AF + (size_t)id * 8) = a;
}

// ---------------------------------------------------------------- staging

// fp32 NHWC -> bf16 CX [n][yp 264][c 16][x 264], pad 4. Block = one (n,yp).
__global__ __launch_bounds__(256) void img_to_cx(
    const float4* __restrict__ src4, unsigned short* __restrict__ dst)
{
    __shared__ unsigned short lds[16][264];
    int n = blockIdx.x & 7;
    int yp = blockIdx.x >> 3;
    int y = yp - 4;
    int t = threadIdx.x;
    unsigned short* drow = dst + ((size_t)(n * 264 + yp) * 16) * 264;

    if ((unsigned)y < 256u) {
        for (int task = t; task < 1056; task += 256) {
            int px = task >> 2, cg = task & 3;
            int xs = px - 4;
            bool ok = (unsigned)xs < 256u;
            int xc = min(max(xs, 0), 255);
            float4 v = src4[((size_t)(n * 256 + y) * 256 + xc) * 4 + cg];
            lds[cg * 4 + 0][px] = (unsigned short)(ok ? f2bf(v.x) : 0);
            lds[cg * 4 + 1][px] = (unsigned short)(ok ? f2bf(v.y) : 0);
            lds[cg * 4 + 2][px] = (unsigned short)(ok ? f2bf(v.z) : 0);
            lds[cg * 4 + 3][px] = (unsigned short)(ok ? f2bf(v.w) : 0);
        }
        __syncthreads();
        for (int task = t; task < 528; task += 256) {
            int c = task / 33, xg = task - c * 33;
            short8v v = *(const short8v*)&lds[c][xg * 8];
            *(short8v*)(drow + (size_t)c * 264 + xg * 8) = v;
        }
    } else {
        short8v z = {0, 0, 0, 0, 0, 0, 0, 0};
        for (int task = t; task < 528; task += 256) {
            int c = task / 33, xg = task - c * 33;
            *(short8v*)(drow + (size_t)c * 264 + xg * 8) = z;
        }
    }
}

// Zero the 8-wide pad borders of the CX lo buffers, 16B stores.
static __device__ __forceinline__ void zero_cx_vec(
    unsigned short* buf, int W, int id)
{
    int Wp = W + 16, Wv = Wp >> 3;
    int rowT = 16 * 16 * Wv;
    int perN = rowT + W * 32;
    int n = id / perN;
    int r = id - n * perN;
    int y, c, xv;
    if (r < rowT) {
        int ry = r / (16 * Wv);
        int rem = r - ry * (16 * Wv);
        c = rem / Wv;
        xv = rem - c * Wv;
        y = (ry < 8) ? ry : ry + W;
    } else {
        int r2 = r - rowT;
        y = 8 + (r2 >> 5);
        int rem = r2 & 31;
        c = rem >> 1;
        xv = (rem & 1) ? (Wv - 1) : 0;
    }
    short8v z = {0, 0, 0, 0, 0, 0, 0, 0};
    *(short8v*)(buf + ((size_t)(n * Wp + y) * 16 + c) * Wp + xv * 8) = z;
}

__global__ __launch_bounds__(256) void zero_pads_cx(
    unsigned short* __restrict__ L0, unsigned short* __restrict__ L1,
    unsigned short* __restrict__ L2, unsigned short* __restrict__ L3)
{
    int b = blockIdx.x, t = threadIdx.x;
    if (b < 528)       zero_cx_vec(L0, 256, b * 256 + t);
    else if (b < 800)  zero_cx_vec(L1, 128, (b - 528) * 256 + t);
    else if (b < 944)  zero_cx_vec(L2, 64,  (b - 800) * 256 + t);
    else if (b < 1024) zero_cx_vec(L3, 32,  (b - 944) * 256 + t);
}

// ---------------------------------------------------------------- MFMA convs

#define MFMA16 __builtin_amdgcn_mfma_f32_16x16x32_bf16
#define MFMA32 __builtin_amdgcn_mfma_f32_32x32x16_bf16

// hi0 + lo0 from IMG CX (pad 4), 32x32x16, M = 2 rows x 2 filt x 8 px.
// grid 1024: n=b&7, q=b>>3 (128/img): xseg=q&15, yq=q>>4 in [0,8).
__global__ __launch_bounds__(256) void dual_mfma32(
    const unsigned short* __restrict__ img,
    float* __restrict__ hi0, unsigned short* __restrict__ lo0,
    const unsigned short* __restrict__ AF)
{
    const int RS = 16 * 264;
    int n = blockIdx.x & 7;
    int q = blockIdx.x >> 3;
    int xseg = q & 15, yq = q >> 4;
    int t = threadIdx.x, wv = t >> 6, l = t & 63;
    int j = l & 31, pg = j >> 4, c = j & 15, kb = (l >> 5) * 8, hi = l >> 5;
    int x0 = xseg * 16;
    int pbase = (yq * 4 + wv) * 4;               // y-pair base

    short8v A[10];
    #pragma unroll
    for (int i = 0; i < 10; ++i)
        A[i] = *(const short8v*)(AF + ((size_t)((9 + i) * 64 + l)) * 8);

    #pragma unroll 1
    for (int tp = 0; tp < 4; ++tp) {
        int y = (pbase + tp) * 2;
        const unsigned short* base =
            img + ((size_t)(n * 264 + y) * 16 + c) * 264 + x0 + pg * 8 + kb;
        f32x16 acc = {};
        #pragma unroll
        for (int i = 0; i < 10; ++i) {
            short8v B = *(const short8v*)(base + (size_t)i * RS);
            acc = MFMA32(A[i], B, acc, 0, 0, 0);
        }
        // reg r: m=(r&3)+8*(r>>2)+4*hi; ry=m>>4, f=(m>>3)&1, p=m&7.
        // r 0-3: ry0 f0 | 4-7: ry0 f1 | 8-11: ry1 f0 | 12-15: ry1 f1.
        #pragma unroll
        for (int ry = 0; ry < 2; ++ry) {
            size_t hb = ((size_t)(n * 256 + y + ry) * 256 + x0 + pg * 8) * 16 + c;
            #pragma unroll
            for (int rr = 0; rr < 4; ++rr) {
                int r = ry * 8 + rr;
                int p = rr + 4 * hi;
                nt_storef(hi0 + hb + (size_t)p * 16, acc[r]);
            }
            size_t lb = ((size_t)(n * 272 + y + ry + 8) * 16 + c) * 272
                        + (x0 + pg * 8 + 4 * hi + 8);
            int r0 = ry * 8 + 4;
            *(unsigned*)(lo0 + lb)     = pack2(acc[r0],     acc[r0 + 1]);
            *(unsigned*)(lo0 + lb + 2) = pack2(acc[r0 + 2], acc[r0 + 3]);
        }
    }
}

// 4 band convs, 32x32x16, M = 4 bands x 8 px. One MFMA per dy.
// grid/8 = (W/16)*(W/16): xseg=q&(XS-1), yq=q>>(LOGW-4).
template <int LOGW>
__global__ __launch_bounds__(256) void bands_mfma32(
    const unsigned short* __restrict__ in,
    float* __restrict__ b0, float* __restrict__ b1,
    float* __restrict__ b2, float* __restrict__ b3,
    const unsigned short* __restrict__ AF)
{
    const int W = 1 << LOGW, Wp = W + 16, XS = W / 16, RS = 16 * Wp;
    int n = blockIdx.x & 7;
    int q = blockIdx.x >> 3;
    int xseg = q & (XS - 1), yq = q >> (LOGW - 4);
    int t = threadIdx.x, wv = t >> 6, l = t & 63;
    int j = l & 31, pg = j >> 4, c = j & 15, kb = (l >> 5) * 8, hi = l >> 5;
    int x0 = xseg * 16;
    int ybase = (yq * 4 + wv) * 4;

    short8v A[9];
    #pragma unroll
    for (int dy = 0; dy < 9; ++dy)
        A[dy] = *(const short8v*)(AF + ((size_t)(dy * 64 + l)) * 8);

    #pragma unroll 1
    for (int ty = 0; ty < 4; ++ty) {
        int y = ybase + ty;
        // B[k] = row[x0+pg*8+k-4]; padded x = x0+pg*8+k+4
        const unsigned short* base =
            in + ((size_t)(n * Wp + y + 4) * 16 + c) * Wp + x0 + pg * 8 + kb + 4;
        f32x16 acc = {};
        #pragma unroll
        for (int dy = 0; dy < 9; ++dy) {
            short8v B = *(const short8v*)(base + (size_t)dy * RS);
            acc = MFMA32(A[dy], B, acc, 0, 0, 0);
        }
        // reg r: f=r>>2, p=(r&3)+4*hi; px = x0+pg*8+p
        size_t ob = ((size_t)(n * W + y) * W + x0 + pg * 8) * 16 + c;
        #pragma unroll
        for (int rr = 0; rr < 4; ++rr) {
            size_t o = ob + (size_t)(rr + 4 * hi) * 16;
            nt_storef(b0 + o, acc[rr]);
            nt_storef(b1 + o, acc[4 + rr]);
            nt_storef(b2 + o, acc[8 + rr]);
            nt_storef(b3 + o, acc[12 + rr]);
        }
    }
}

// 17x17 stride-2 downsample (16x16x32, k-split). AF rows 19/36.
template <int LOGW, bool OUTF32>
__global__ __launch_bounds__(256) void down_mfma(
    const unsigned short* __restrict__ in, void* __restrict__ outp,
    const unsigned short* __restrict__ AF)
{
    const int W = 1 << LOGW, Wpi = W + 16, Wo = W >> 1, Wpo = Wo + 16;
    const int XS = Wo / 16, RS = 16 * Wpi;
    int n = blockIdx.x & 7;
    int q = blockIdx.x >> 3;
    int xseg = q & (XS - 1), yq = q >> (LOGW - 5);
    int t = threadIdx.x, wv = t >> 6, l = t & 63;
    int m = l & 15, g = l >> 4, kb = g * 8;
    int x0 = xseg * 16;
    int ybase = (yq * 4 + wv) * 4;
    int off2 = (g < 2) ? 32 : 0;

    short8v A1[17], A2[17];
    #pragma unroll
    for (int dy = 0; dy < 17; ++dy) {
        A1[dy] = *(const short8v*)(AF + ((size_t)((19 + dy) * 64 + l)) * 8);
        A2[dy] = *(const short8v*)(AF + ((size_t)((36 + dy) * 64 + l)) * 8);
    }

    #pragma unroll 1
    for (int ty = 0; ty < 4; ++ty) {
        int yo = ybase + ty;
        const unsigned short* base =
            in + ((size_t)(n * Wpi + 2 * yo) * 16 + m) * Wpi + 2 * x0 + kb;
        f32x4 aA = {0, 0, 0, 0}, aB = {0, 0, 0, 0};
        #pragma unroll
        for (int dy = 0; dy < 17; ++dy) {
            short8v B1 = *(const short8v*)(base + (size_t)dy * RS);
            short8v B2 = *(const short8v*)(base + (size_t)dy * RS + off2);
            aA = MFMA16(A1[dy], B1, aA, 0, 0, 0);
            aB = MFMA16(A2[dy], B2, aB, 0, 0, 0);
        }
        f32x4 acc = aA + aB;
        if (OUTF32) {
            float* o = (float*)outp;
            size_t ob = ((size_t)(n * Wo + yo) * Wo + x0 + g * 4) * 16 + m;
            #pragma unroll
            for (int r = 0; r < 4; ++r) nt_storef(o + ob + (size_t)r * 16, acc[r]);
        } else {
            unsigned short* o = (unsigned short*)outp;
            size_t lb = ((size_t)(n * Wpo + yo + 8) * 16 + m) * Wpo + (x0 + 8 + g * 4);
            *(unsigned*)(o + lb)     = pack2(acc[0], acc[1]);
            *(unsigned*)(o + lb + 2) = pack2(acc[2], acc[3]);
        }
    }
}

// ---------------------------------------------------------------- launch

extern "C" void kernel_launch(void* const* d_in, const int* in_sizes, int n_in,
                              void* d_out, int out_size, void* d_ws, size_t ws_size,
                              hipStream_t stream) {
    const float* image   = (const float*)d_in[0];
    const float* lo0filt = (const float*)d_in[1];
    const float* hi0filt = (const float*)d_in[2];
    const float* lofilt  = (const float*)d_in[3];
    const float* bfilts  = (const float*)d_in[4];
    float* out = (float*)d_out;

    const int N = 8, C = 16;
    size_t sz[5];
    const int Ws[5] = {256, 128, 64, 32, 16};
    for (int s = 0; s < 5; ++s) sz[s] = (size_t)N * Ws[s] * Ws[s] * C;

    // Workspace (ushort units): AF table, IMG CX (pad4), L0..L3 CX (pad8).
    unsigned short* wsu = (unsigned short*)d_ws;
    unsigned short* AF  = wsu;                       // 53*64*8 = 27136 -> pad 32768
    unsigned short* IMG = AF + 32768;
    unsigned short* L0 = IMG + (size_t)N * 264 * 16 * 264;
    unsigned short* L1 = L0 + (size_t)N * 272 * 16 * 272;
    unsigned short* L2 = L1 + (size_t)N * 144 * 16 * 144;
    unsigned short* L3 = L2 + (size_t)N * 80 * 16 * 80;

    // Output layout (reversed pyramid, flat):
    // [ lo_final | s=3 b=3..0 | s=2 b=3..0 | s=1 b=3..0 | s=0 b=3..0 | hi0 ]
    float* out_lofinal = out;
    size_t o = sz[4];
    float* band_ptr[4][4];
    for (int s = 3; s >= 0; --s)
        for (int b = 3; b >= 0; --b) { band_ptr[s][b] = out + o; o += sz[s]; }
    float* out_hi0 = out + o;

    build_frags<<<14, 256, 0, stream>>>(bfilts, hi0filt, lo0filt, lofilt, AF);
    zero_pads_cx<<<1024, 256, 0, stream>>>(L0, L1, L2, L3);
    img_to_cx<<<2112, 256, 0, stream>>>((const float4*)image, IMG);
    dual_mfma32<<<1024, 256, 0, stream>>>(IMG, out_hi0, L0, AF);
    down_mfma<8, false><<<512, 256, 0, stream>>>(L0, L1, AF);
    bands_mfma32<8><<<2048, 256, 0, stream>>>(
        L0, band_ptr[0][0], band_ptr[0][1], band_ptr[0][2], band_ptr[0][3], AF);
    down_mfma<7, false><<<128, 256, 0, stream>>>(L1, L2, AF);
    bands_mfma32<7><<<512, 256, 0, stream>>>(
        L1, band_ptr[1][0], band_ptr[1][1], band_ptr[1][2], band_ptr[1][3], AF);
    down_mfma<6, false><<<32, 256, 0, stream>>>(L2, L3, AF);
    bands_mfma32<6><<<128, 256, 0, stream>>>(
        L2, band_ptr[2][0], band_ptr[2][1], band_ptr[2][2], band_ptr[2][3], AF);
    down_mfma<5, true><<<8, 256, 0, stream>>>(L3, out_lofinal, AF);
    bands_mfma32<5><<<32, 256, 0, stream>>>(
        L3, band_ptr[3][0], band_ptr[3][1], band_ptr[3][2], band_ptr[3][3], AF);
}